// Round 1
// baseline (734.318 us; speedup 1.0000x reference)
//
#include <hip/hip_runtime.h>

typedef unsigned short u16;
typedef short bfrag __attribute__((ext_vector_type(8)));   // 8 bf16 (4 VGPRs)
typedef float facc  __attribute__((ext_vector_type(4)));   // 4 fp32 acc

#define LOG2E 1.44269504088896340736f

static __device__ __forceinline__ float bf2f(u16 b) {
  union { unsigned u; float f; } v; v.u = ((unsigned)b) << 16; return v.f;
}
static __device__ __forceinline__ u16 f2bf(float x) {  // RNE
  union { float f; unsigned u; } v; v.f = x;
  return (u16)((v.u + 0x7FFFu + ((v.u >> 16) & 1u)) >> 16);
}
static __device__ __forceinline__ void gload_lds16(const u16* g, u16* l) {
  __builtin_amdgcn_global_load_lds((const __attribute__((address_space(1))) void*)g,
                                   (__attribute__((address_space(3))) void*)l,
                                   16, 0, 0);
}

// Kernel 0: f32 -> bf16 RNE pre-convert of x, qkv_w, proj_w (memory-bound, ~48MB)
__global__ __launch_bounds__(256) void convert_kernel(
    const float* __restrict__ x, const float* __restrict__ qw, const float* __restrict__ pw,
    u16* __restrict__ xb, u16* __restrict__ qwb, u16* __restrict__ pwb)
{
  const int NX = 4 * 1024 * 1024, NQ = 3 * 1024 * 1024, NP = 1024 * 1024;
  const int total4 = (NX + NQ + NP) >> 2;
  for (int i = blockIdx.x * blockDim.x + threadIdx.x; i < total4;
       i += gridDim.x * blockDim.x) {
    const int e = i << 2;
    const float* s; u16* d; int off;
    if (e < NX)            { s = x;  d = xb;  off = e; }
    else if (e < NX + NQ)  { s = qw; d = qwb; off = e - NX; }
    else                   { s = pw; d = pwb; off = e - NX - NQ; }
    float4 v = *(const float4*)(s + off);
    ushort4 o;
    o.x = f2bf(v.x); o.y = f2bf(v.y); o.z = f2bf(v.z); o.w = f2bf(v.w);
    *(ushort4*)(d + off) = o;
  }
}

// C[m][n] = sum_k A[m][k] * B[n][k]   (B^T GEMM, bf16). 128x128 tile / 256 thr.
static __device__ __forceinline__ void gemm128_bt(
    const u16* __restrict__ A, const u16* __restrict__ B, int K,
    int m0, int n0, u16* As, u16* Bs, facc acc[4][4])
{
  const int lane = threadIdx.x & 63;
  const int wv   = threadIdx.x >> 6;
  const int quad = lane >> 4;
  const int l15  = lane & 15;
  const int wm = wv >> 1, wn = wv & 1;
  const int srow = lane >> 2;        // 16 rows per wave-call
  const int skb  = (lane & 3) * 8;   // 4 x 8 bf16 = 64B per row

  facc zero = {0.f, 0.f, 0.f, 0.f};
#pragma unroll
  for (int i = 0; i < 4; ++i)
#pragma unroll
    for (int j = 0; j < 4; ++j) acc[i][j] = zero;

  const int nIter = K >> 5;
  for (int kk = 0; kk < nIter; ++kk) {
    const int k0 = kk << 5;
    __syncthreads();                  // previous compute done before LDS overwrite
#pragma unroll
    for (int c = 0; c < 2; ++c) {
      const int seg = wv * 2 + c;     // 8 segs x 16 rows = 128 rows
      gload_lds16(A + (long)(m0 + seg * 16 + srow) * K + k0 + skb, As + seg * 512);
      gload_lds16(B + (long)(n0 + seg * 16 + srow) * K + k0 + skb, Bs + seg * 512);
    }
    __syncthreads();                  // compiler drains vmcnt before barrier
    bfrag af[4], bf[4];
#pragma unroll
    for (int i = 0; i < 4; ++i)
      af[i] = *(const bfrag*)(As + (wm * 64 + i * 16 + l15) * 32 + quad * 8);
#pragma unroll
    for (int j = 0; j < 4; ++j)
      bf[j] = *(const bfrag*)(Bs + (wn * 64 + j * 16 + l15) * 32 + quad * 8);
#pragma unroll
    for (int i = 0; i < 4; ++i)
#pragma unroll
      for (int j = 0; j < 4; ++j)
        acc[i][j] = __builtin_amdgcn_mfma_f32_16x16x32_bf16(af[i], bf[j], acc[i][j], 0, 0, 0);
  }
}

// Kernel 1: qkv = x @ qkv_w^T + qkv_b.  Scatter: Q(scaled) [B,H,N,D], K [B,H,N,D],
// V transposed [B,H,D,N] so PV's B-operand is contiguous.
__global__ __launch_bounds__(256) void qkv_gemm_kernel(
    const u16* __restrict__ x, const u16* __restrict__ w,
    const float* __restrict__ qb, const float* __restrict__ vb,
    u16* __restrict__ Q, u16* __restrict__ Kd, u16* __restrict__ Vt)
{
  __shared__ u16 As[128 * 32];
  __shared__ u16 Bs[128 * 32];
  facc acc[4][4];
  const int m0 = blockIdx.y * 128;   // rows of x (B*N = 4096)
  const int n0 = blockIdx.x * 128;   // cols (3C = 3072)
  gemm128_bt(x, w, 1024, m0, n0, As, Bs, acc);

  const int lane = threadIdx.x & 63;
  const int wv = threadIdx.x >> 6;
  const int quad = lane >> 4, l15 = lane & 15;
  const int wm = wv >> 1, wn = wv & 1;
  const int ncb = n0 + wn * 64;        // wave-uniform: one (which, h) per wave
  const int which = ncb >> 10;         // 0=Q 1=K 2=V
  const int h = (ncb >> 6) & 15;

#pragma unroll
  for (int j = 0; j < 4; ++j) {
    const int d = j * 16 + l15;        // d within head
    const int n_g = ncb + d;
#pragma unroll
    for (int i = 0; i < 4; ++i) {
      const int mg0 = m0 + wm * 64 + i * 16 + quad * 4;   // 4-aligned
      const int b  = mg0 >> 11;
      const int ns = mg0 & 2047;
      if (which == 0) {
        const float qbv = qb[n_g];
#pragma unroll
        for (int r = 0; r < 4; ++r)
          Q[(((long)(b * 16 + h) * 2048 + ns + r) << 6) + d] =
              f2bf((acc[i][j][r] + qbv) * 0.125f);          // (x@W+qb)*SCALE
      } else if (which == 1) {
#pragma unroll
        for (int r = 0; r < 4; ++r)
          Kd[(((long)(b * 16 + h) * 2048 + ns + r) << 6) + d] = f2bf(acc[i][j][r]);
      } else {
        const float vbv = vb[n_g - 2048];
        ushort4 pk;                                          // 4 consecutive n -> 8B store
        pk.x = f2bf(acc[i][j][0] + vbv);
        pk.y = f2bf(acc[i][j][1] + vbv);
        pk.z = f2bf(acc[i][j][2] + vbv);
        pk.w = f2bf(acc[i][j][3] + vbv);
        *(ushort4*)(Vt + (((long)((b * 16 + h) * 64 + d)) << 11) + ns) = pk;
      }
    }
  }
}

// Kernel 2: flash attention. 1 block = (bh, 64 q-rows); 1 wave = 16 q-rows.
// v2: KVBLK=64, barrier-free (P is wave-private), XOR-swizzled P tile,
// register-prefetched bias (nontemporal), V frags batched before PV so the
// vmcnt wait for V does not drain the bias prefetch.
__global__ __launch_bounds__(256) void attn_kernel(
    const u16* __restrict__ Q, const u16* __restrict__ Kd, const u16* __restrict__ Vt,
    const float* __restrict__ bias, u16* __restrict__ AO)
{
  __shared__ u16 P[4][16 * 64];   // wave-private P tiles (16q x 64k bf16), swizzled
  const int lane = threadIdx.x & 63;
  const int wv = threadIdx.x >> 6;
  const int quad = lane >> 4, l15 = lane & 15;
  const int bh = blockIdx.x >> 5;
  const int qt = blockIdx.x & 31;
  const int h = bh & 15;
  const int b = bh >> 4;
  const int q0 = qt * 64 + wv * 16;
  const long baseN = (long)bh << 17;   // bh * 2048 * 64

  // Q A-frags for this wave's 16 rows (already scaled+biased)
  bfrag qf0 = *(const bfrag*)(Q + baseN + (long)(q0 + l15) * 64 + quad * 8);
  bfrag qf1 = *(const bfrag*)(Q + baseN + (long)(q0 + l15) * 64 + 32 + quad * 8);

  facc o[4];
  float m_i[4], l_i[4];
  facc zero = {0.f, 0.f, 0.f, 0.f};
#pragma unroll
  for (int t = 0; t < 4; ++t) o[t] = zero;
#pragma unroll
  for (int r = 0; r < 4; ++r) { m_i[r] = -1e30f; l_i[r] = 0.f; }

  const float* brow = bias + ((long)h << 22) + ((long)q0 << 11);
  char* PwB = (char*)&P[wv][0];

  // bias prefetch registers: bn[kt*4+r] = bias[q=q0+quad*4+r][k0+kt*16+l15]
  float bn[16];
#pragma unroll
  for (int kt = 0; kt < 4; ++kt)
#pragma unroll
    for (int r = 0; r < 4; ++r)
      bn[kt * 4 + r] =
          __builtin_nontemporal_load(brow + (long)(quad * 4 + r) * 2048 + kt * 16 + l15);

  for (int k0 = 0; k0 < 2048; k0 += 64) {
    // S = Q K^T for 4 x (16q x 16k) tiles; K rows load as A-style frags = B^T operand
    facc s[4];
#pragma unroll
    for (int kt = 0; kt < 4; ++kt) {
      const u16* kb = Kd + baseN + (long)(k0 + kt * 16 + l15) * 64;
      bfrag kf0 = *(const bfrag*)(kb + quad * 8);
      bfrag kf1 = *(const bfrag*)(kb + 32 + quad * 8);
      facc z = zero;
      z = __builtin_amdgcn_mfma_f32_16x16x32_bf16(qf0, kf0, z, 0, 0, 0);
      z = __builtin_amdgcn_mfma_f32_16x16x32_bf16(qf1, kf1, z, 0, 0, 0);
      s[kt] = z;
    }
    // + rel_pos_bias from the prefetched registers (loaded last iteration)
#pragma unroll
    for (int kt = 0; kt < 4; ++kt)
#pragma unroll
      for (int r = 0; r < 4; ++r)
        s[kt][r] += bn[kt * 4 + r];

    // online softmax: row reductions across the 16 lanes of the quad
    float alpha[4];
#pragma unroll
    for (int r = 0; r < 4; ++r) {
      float v = fmaxf(fmaxf(s[0][r], s[1][r]), fmaxf(s[2][r], s[3][r]));
      v = fmaxf(v, __shfl_xor(v, 1, 16));
      v = fmaxf(v, __shfl_xor(v, 2, 16));
      v = fmaxf(v, __shfl_xor(v, 4, 16));
      v = fmaxf(v, __shfl_xor(v, 8, 16));
      const float mn = fmaxf(m_i[r], v);
      alpha[r] = exp2f((m_i[r] - mn) * LOG2E);
      m_i[r] = mn;
    }
#pragma unroll
    for (int r = 0; r < 4; ++r) {
      const float p0 = exp2f((s[0][r] - m_i[r]) * LOG2E);
      const float p1 = exp2f((s[1][r] - m_i[r]) * LOG2E);
      const float p2 = exp2f((s[2][r] - m_i[r]) * LOG2E);
      const float p3 = exp2f((s[3][r] - m_i[r]) * LOG2E);
      s[0][r] = p0; s[1][r] = p1; s[2][r] = p2; s[3][r] = p3;
      float v = (p0 + p1) + (p2 + p3);
      v += __shfl_xor(v, 1, 16);
      v += __shfl_xor(v, 2, 16);
      v += __shfl_xor(v, 4, 16);
      v += __shfl_xor(v, 8, 16);
      l_i[r] = l_i[r] * alpha[r] + v;
    }
#pragma unroll
    for (int t = 0; t < 4; ++t)
#pragma unroll
      for (int r = 0; r < 4; ++r) o[t][r] *= alpha[r];

    // P: C-layout -> LDS (XOR-swizzled: byte ^= (row&7)<<4 kills the 16-way
    // ds_read_b128 bank conflict of the 128B row stride). Wave-private: no barrier.
#pragma unroll
    for (int kt = 0; kt < 4; ++kt)
#pragma unroll
      for (int r = 0; r < 4; ++r) {
        const int row = quad * 4 + r;
        int bo = row * 128 + (kt * 16 + l15) * 2;
        bo ^= (row & 7) << 4;
        *(u16*)(PwB + bo) = f2bf(s[kt][r]);
      }

    // A-frags of P for the two 32-key chunks (same swizzle, row = l15)
    bfrag pf[2];
#pragma unroll
    for (int p = 0; p < 2; ++p) {
      int bo = l15 * 128 + p * 64 + quad * 16;
      bo ^= (l15 & 7) << 4;
      pf[p] = *(const bfrag*)(PwB + bo);
    }

    // issue ALL V loads first ...
    bfrag vfr[4][2];
#pragma unroll
    for (int t = 0; t < 4; ++t) {
      const u16* vrow = Vt + baseN + (((long)(t * 16 + l15)) << 11) + k0;
#pragma unroll
      for (int p = 0; p < 2; ++p)
        vfr[t][p] = *(const bfrag*)(vrow + p * 32 + quad * 8);
    }
    // ... THEN issue next tile's bias prefetch (newest in the vmcnt queue, so
    // waiting for V = vmcnt(16): bias loads stay in flight across the PV MFMAs
    // and the next iteration's QK section — covers the ~900cy HBM latency).
    if (k0 + 64 < 2048) {
      const float* bnx = brow + k0 + 64;
#pragma unroll
      for (int kt = 0; kt < 4; ++kt)
#pragma unroll
        for (int r = 0; r < 4; ++r)
          bn[kt * 4 + r] =
              __builtin_nontemporal_load(bnx + (long)(quad * 4 + r) * 2048 + kt * 16 + l15);
    }

    // O += P V over both key chunks
#pragma unroll
    for (int t = 0; t < 4; ++t)
#pragma unroll
      for (int p = 0; p < 2; ++p)
        o[t] = __builtin_amdgcn_mfma_f32_16x16x32_bf16(pf[p], vfr[t][p], o[t], 0, 0, 0);
  }

  // epilogue: O/l -> [B, N, H*D] (bf16 intermediate)
#pragma unroll
  for (int r = 0; r < 4; ++r) l_i[r] = 1.0f / l_i[r];
#pragma unroll
  for (int t = 0; t < 4; ++t)
#pragma unroll
    for (int r = 0; r < 4; ++r) {
      const int row = q0 + quad * 4 + r;
      AO[(((long)(b * 2048 + row)) << 10) + h * 64 + t * 16 + l15] = f2bf(o[t][r] * l_i[r]);
    }
}

// Kernel 3: out = AO @ proj_w^T + proj_b  (f32 output)
__global__ __launch_bounds__(256) void proj_kernel(
    const u16* __restrict__ Ain, const u16* __restrict__ w,
    const float* __restrict__ pb, float* __restrict__ out)
{
  __shared__ u16 As[128 * 32];
  __shared__ u16 Bs[128 * 32];
  facc acc[4][4];
  const int m0 = blockIdx.y * 128;
  const int n0 = blockIdx.x * 128;
  gemm128_bt(Ain, w, 1024, m0, n0, As, Bs, acc);

  const int lane = threadIdx.x & 63;
  const int wv = threadIdx.x >> 6;
  const int quad = lane >> 4, l15 = lane & 15;
  const int wm = wv >> 1, wn = wv & 1;
#pragma unroll
  for (int j = 0; j < 4; ++j) {
    const int n_g = n0 + wn * 64 + j * 16 + l15;
    const float pbv = pb[n_g];
#pragma unroll
    for (int i = 0; i < 4; ++i) {
      const int mg0 = m0 + wm * 64 + i * 16 + quad * 4;
#pragma unroll
      for (int r = 0; r < 4; ++r)
        out[(((long)(mg0 + r)) << 10) + n_g] = acc[i][j][r] + pbv;
    }
  }
}

extern "C" void kernel_launch(void* const* d_in, const int* in_sizes, int n_in,
                              void* d_out, int out_size, void* d_ws, size_t ws_size,
                              hipStream_t stream)
{
  const float* x    = (const float*)d_in[0];   // [2,2048,1024] f32
  const float* bias = (const float*)d_in[1];   // [16,2048,2048] f32
  const float* qkvw = (const float*)d_in[2];   // [3072,1024] f32
  const float* qb   = (const float*)d_in[3];   // [1024] f32
  const float* vb   = (const float*)d_in[4];   // [1024] f32
  const float* pw   = (const float*)d_in[5];   // [1024,1024] f32
  const float* pb   = (const float*)d_in[6];   // [1024] f32
  float* out = (float*)d_out;                  // [2,2048,1024] f32

  char* ws = (char*)d_ws;                      // 48 MiB used
  u16* Q    = (u16*)(ws);                                  // [B,H,N,D]  8 MiB
  u16* Kd   = (u16*)(ws + (size_t)8  * 1024 * 1024);       // [B,H,N,D]  8 MiB
  u16* Vt   = (u16*)(ws + (size_t)16 * 1024 * 1024);       // [B,H,D,N]  8 MiB
  u16* AO   = (u16*)(ws + (size_t)24 * 1024 * 1024);       // [B,N,C]    8 MiB
  u16* xb   = (u16*)(ws + (size_t)32 * 1024 * 1024);       // x bf16     8 MiB
  u16* qwb  = (u16*)(ws + (size_t)40 * 1024 * 1024);       // qkv_w bf16 6 MiB
  u16* pwb  = (u16*)(ws + (size_t)46 * 1024 * 1024);       // proj_w bf16 2 MiB

  hipLaunchKernelGGL(convert_kernel, dim3(1024), dim3(256), 0, stream,
                     x, qkvw, pw, xb, qwb, pwb);
  hipLaunchKernelGGL(qkv_gemm_kernel, dim3(24, 32), dim3(256), 0, stream,
                     xb, qwb, qb, vb, Q, Kd, Vt);
  hipLaunchKernelGGL(attn_kernel, dim3(1024), dim3(256), 0, stream,
                     Q, Kd, Vt, bias, AO);
  hipLaunchKernelGGL(proj_kernel, dim3(8, 32), dim3(256), 0, stream,
                     AO, pwb, pb, out);
}

// Round 2
// 671.766 us; speedup vs baseline: 1.0931x; 1.0931x over previous
//
#include <hip/hip_runtime.h>

typedef unsigned short u16;
typedef short bfrag __attribute__((ext_vector_type(8)));   // 8 bf16 (4 VGPRs)
typedef float facc  __attribute__((ext_vector_type(4)));   // 4 fp32 acc

#define LOG2E 1.44269504088896340736f

static __device__ __forceinline__ float bf2f(u16 b) {
  union { unsigned u; float f; } v; v.u = ((unsigned)b) << 16; return v.f;
}
static __device__ __forceinline__ u16 f2bf(float x) {  // RNE
  union { float f; unsigned u; } v; v.f = x;
  return (u16)((v.u + 0x7FFFu + ((v.u >> 16) & 1u)) >> 16);
}
static __device__ __forceinline__ void gload_lds16(const u16* g, u16* l) {
  __builtin_amdgcn_global_load_lds((const __attribute__((address_space(1))) void*)g,
                                   (__attribute__((address_space(3))) void*)l,
                                   16, 0, 0);
}
static __device__ __forceinline__ void gload_lds16f(const float* g, float* l) {
  __builtin_amdgcn_global_load_lds((const __attribute__((address_space(1))) void*)g,
                                   (__attribute__((address_space(3))) void*)l,
                                   16, 0, 0);
}

// Kernel 0: f32 -> bf16 RNE pre-convert of x, qkv_w, proj_w (memory-bound, ~48MB)
__global__ __launch_bounds__(256) void convert_kernel(
    const float* __restrict__ x, const float* __restrict__ qw, const float* __restrict__ pw,
    u16* __restrict__ xb, u16* __restrict__ qwb, u16* __restrict__ pwb)
{
  const int NX = 4 * 1024 * 1024, NQ = 3 * 1024 * 1024, NP = 1024 * 1024;
  const int total4 = (NX + NQ + NP) >> 2;
  for (int i = blockIdx.x * blockDim.x + threadIdx.x; i < total4;
       i += gridDim.x * blockDim.x) {
    const int e = i << 2;
    const float* s; u16* d; int off;
    if (e < NX)            { s = x;  d = xb;  off = e; }
    else if (e < NX + NQ)  { s = qw; d = qwb; off = e - NX; }
    else                   { s = pw; d = pwb; off = e - NX - NQ; }
    float4 v = *(const float4*)(s + off);
    ushort4 o;
    o.x = f2bf(v.x); o.y = f2bf(v.y); o.z = f2bf(v.z); o.w = f2bf(v.w);
    *(ushort4*)(d + off) = o;
  }
}

// C[m][n] = sum_k A[m][k] * B[n][k]   (B^T GEMM, bf16). 128x128 tile / 256 thr.
static __device__ __forceinline__ void gemm128_bt(
    const u16* __restrict__ A, const u16* __restrict__ B, int K,
    int m0, int n0, u16* As, u16* Bs, facc acc[4][4])
{
  const int lane = threadIdx.x & 63;
  const int wv   = threadIdx.x >> 6;
  const int quad = lane >> 4;
  const int l15  = lane & 15;
  const int wm = wv >> 1, wn = wv & 1;
  const int srow = lane >> 2;        // 16 rows per wave-call
  const int skb  = (lane & 3) * 8;   // 4 x 8 bf16 = 64B per row

  facc zero = {0.f, 0.f, 0.f, 0.f};
#pragma unroll
  for (int i = 0; i < 4; ++i)
#pragma unroll
    for (int j = 0; j < 4; ++j) acc[i][j] = zero;

  const int nIter = K >> 5;
  for (int kk = 0; kk < nIter; ++kk) {
    const int k0 = kk << 5;
    __syncthreads();                  // previous compute done before LDS overwrite
#pragma unroll
    for (int c = 0; c < 2; ++c) {
      const int seg = wv * 2 + c;     // 8 segs x 16 rows = 128 rows
      gload_lds16(A + (long)(m0 + seg * 16 + srow) * K + k0 + skb, As + seg * 512);
      gload_lds16(B + (long)(n0 + seg * 16 + srow) * K + k0 + skb, Bs + seg * 512);
    }
    __syncthreads();                  // compiler drains vmcnt before barrier
    bfrag af[4], bf[4];
#pragma unroll
    for (int i = 0; i < 4; ++i)
      af[i] = *(const bfrag*)(As + (wm * 64 + i * 16 + l15) * 32 + quad * 8);
#pragma unroll
    for (int j = 0; j < 4; ++j)
      bf[j] = *(const bfrag*)(Bs + (wn * 64 + j * 16 + l15) * 32 + quad * 8);
#pragma unroll
    for (int i = 0; i < 4; ++i)
#pragma unroll
      for (int j = 0; j < 4; ++j)
        acc[i][j] = __builtin_amdgcn_mfma_f32_16x16x32_bf16(af[i], bf[j], acc[i][j], 0, 0, 0);
  }
}

// Kernel 1: qkv = x @ qkv_w^T + qkv_b.  Scatter: Q(scaled) [B,H,N,D], K [B,H,N,D],
// V transposed [B,H,D,N] so PV's B-operand is contiguous.
__global__ __launch_bounds__(256) void qkv_gemm_kernel(
    const u16* __restrict__ x, const u16* __restrict__ w,
    const float* __restrict__ qb, const float* __restrict__ vb,
    u16* __restrict__ Q, u16* __restrict__ Kd, u16* __restrict__ Vt)
{
  __shared__ u16 As[128 * 32];
  __shared__ u16 Bs[128 * 32];
  facc acc[4][4];
  const int m0 = blockIdx.y * 128;   // rows of x (B*N = 4096)
  const int n0 = blockIdx.x * 128;   // cols (3C = 3072)
  gemm128_bt(x, w, 1024, m0, n0, As, Bs, acc);

  const int lane = threadIdx.x & 63;
  const int wv = threadIdx.x >> 6;
  const int quad = lane >> 4, l15 = lane & 15;
  const int wm = wv >> 1, wn = wv & 1;
  const int ncb = n0 + wn * 64;        // wave-uniform: one (which, h) per wave
  const int which = ncb >> 10;         // 0=Q 1=K 2=V
  const int h = (ncb >> 6) & 15;

#pragma unroll
  for (int j = 0; j < 4; ++j) {
    const int d = j * 16 + l15;        // d within head
    const int n_g = ncb + d;
#pragma unroll
    for (int i = 0; i < 4; ++i) {
      const int mg0 = m0 + wm * 64 + i * 16 + quad * 4;   // 4-aligned
      const int b  = mg0 >> 11;
      const int ns = mg0 & 2047;
      if (which == 0) {
        const float qbv = qb[n_g];
#pragma unroll
        for (int r = 0; r < 4; ++r)
          Q[(((long)(b * 16 + h) * 2048 + ns + r) << 6) + d] =
              f2bf((acc[i][j][r] + qbv) * 0.125f);          // (x@W+qb)*SCALE
      } else if (which == 1) {
#pragma unroll
        for (int r = 0; r < 4; ++r)
          Kd[(((long)(b * 16 + h) * 2048 + ns + r) << 6) + d] = f2bf(acc[i][j][r]);
      } else {
        const float vbv = vb[n_g - 2048];
        ushort4 pk;                                          // 4 consecutive n -> 8B store
        pk.x = f2bf(acc[i][j][0] + vbv);
        pk.y = f2bf(acc[i][j][1] + vbv);
        pk.z = f2bf(acc[i][j][2] + vbv);
        pk.w = f2bf(acc[i][j][3] + vbv);
        *(ushort4*)(Vt + (((long)((b * 16 + h) * 64 + d)) << 11) + ns) = pk;
      }
    }
  }
}

// Kernel 2: flash attention. 1 block = (bh, 64 q-rows); 1 wave = 16 q-rows.
// v3: KVBLK=64, barrier-free, LEAN registers (<=64 -> 8 waves/SIMD cap),
// bias staged to LDS via global_load_lds one iteration ahead (zero-VGPR
// prefetch), slot-interleaved P tile whose ds_read_b128 is linear (lane*16),
// XCD-contiguous block remap so each XCD's 4 bh keep K/V L2-resident.
__global__ __launch_bounds__(256, 4) void attn_kernel(
    const u16* __restrict__ Q, const u16* __restrict__ Kd, const u16* __restrict__ Vt,
    const float* __restrict__ bias, u16* __restrict__ AO)
{
  __shared__ u16 P[4][16 * 64];           // 8 KB: per-wave P, slot-interleaved
  __shared__ float BiasS[4][2][16 * 64];  // 32 KB: per-wave bias tile, dbuf
  const int lane = threadIdx.x & 63;
  const int wv = threadIdx.x >> 6;
  const int quad = lane >> 4, l15 = lane & 15;
  int bid = blockIdx.x;
  bid = (bid & 7) * 128 + (bid >> 3);     // XCD-contiguous remap (1024 % 8 == 0)
  const int bh = bid >> 5;
  const int qt = bid & 31;
  const int h = bh & 15;
  const int b = bh >> 4;
  const int q0 = qt * 64 + wv * 16;
  const long baseN = (long)bh << 17;      // bh * 2048 * 64

  // Q A-frags for this wave's 16 rows (already scaled+biased)
  bfrag qf0 = *(const bfrag*)(Q + baseN + (long)(q0 + l15) * 64 + quad * 8);
  bfrag qf1 = *(const bfrag*)(Q + baseN + (long)(q0 + l15) * 64 + 32 + quad * 8);

  facc o[4];
  float m_i[4], l_i[4];
  facc zero = {0.f, 0.f, 0.f, 0.f};
#pragma unroll
  for (int t = 0; t < 4; ++t) o[t] = zero;
#pragma unroll
  for (int r = 0; r < 4; ++r) { m_i[r] = -1e30f; l_i[r] = 0.f; }

  const float* brow = bias + ((long)h << 22) + ((long)q0 << 11);
  char* PwB = (char*)&P[wv][0];
  float* bS[2] = { &BiasS[wv][0][0], &BiasS[wv][1][0] };

  // prologue: stage bias tile for k0=0 into buf 0 (4 x 1KB direct-to-LDS)
#pragma unroll
  for (int c = 0; c < 4; ++c)
    gload_lds16f(brow + (long)(c * 4 + quad) * 2048 + l15 * 4, bS[0] + c * 256);

  for (int k0 = 0; k0 < 2048; k0 += 64) {
    const float* bsCur = bS[(k0 >> 6) & 1];
    // S = Q K^T for 4 x (16q x 16k) tiles; K rows load as A-style frags = B^T operand
    facc s[4];
#pragma unroll
    for (int kt = 0; kt < 4; ++kt) {
      const u16* kb = Kd + baseN + (long)(k0 + kt * 16 + l15) * 64;
      bfrag kf0 = *(const bfrag*)(kb + quad * 8);
      bfrag kf1 = *(const bfrag*)(kb + 32 + quad * 8);
      facc z = zero;
      z = __builtin_amdgcn_mfma_f32_16x16x32_bf16(qf0, kf0, z, 0, 0, 0);
      z = __builtin_amdgcn_mfma_f32_16x16x32_bf16(qf1, kf1, z, 0, 0, 0);
      s[kt] = z;
    }
    // ensure the staged bias tile (issued last iteration) has landed in LDS.
    // Everything older in the vmem queue (this tile's K frags) is already
    // consumed by the MFMAs above, so this wait is effectively free.
    asm volatile("s_waitcnt vmcnt(0)" ::: "memory");
    // + rel_pos_bias from LDS
#pragma unroll
    for (int kt = 0; kt < 4; ++kt)
#pragma unroll
      for (int r = 0; r < 4; ++r)
        s[kt][r] += bsCur[(quad * 4 + r) * 64 + kt * 16 + l15];

    // issue next tile's bias staging into the other buffer (zero-VGPR prefetch;
    // HBM latency hides under softmax + PV + next QK)
    if (k0 + 64 < 2048) {
      float* bsNxt = bS[((k0 >> 6) + 1) & 1];
      const float* src = brow + k0 + 64;
#pragma unroll
      for (int c = 0; c < 4; ++c)
        gload_lds16f(src + (long)(c * 4 + quad) * 2048 + l15 * 4, bsNxt + c * 256);
    }

    // online softmax: row reductions across the 16 lanes of the quad
    float alpha[4];
#pragma unroll
    for (int r = 0; r < 4; ++r) {
      float v = fmaxf(fmaxf(s[0][r], s[1][r]), fmaxf(s[2][r], s[3][r]));
      v = fmaxf(v, __shfl_xor(v, 1, 16));
      v = fmaxf(v, __shfl_xor(v, 2, 16));
      v = fmaxf(v, __shfl_xor(v, 4, 16));
      v = fmaxf(v, __shfl_xor(v, 8, 16));
      const float mn = fmaxf(m_i[r], v);
      alpha[r] = exp2f((m_i[r] - mn) * LOG2E);
      m_i[r] = mn;
    }
#pragma unroll
    for (int r = 0; r < 4; ++r) {
      const float p0 = exp2f((s[0][r] - m_i[r]) * LOG2E);
      const float p1 = exp2f((s[1][r] - m_i[r]) * LOG2E);
      const float p2 = exp2f((s[2][r] - m_i[r]) * LOG2E);
      const float p3 = exp2f((s[3][r] - m_i[r]) * LOG2E);
      s[0][r] = p0; s[1][r] = p1; s[2][r] = p2; s[3][r] = p3;
      float v = (p0 + p1) + (p2 + p3);
      v += __shfl_xor(v, 1, 16);
      v += __shfl_xor(v, 2, 16);
      v += __shfl_xor(v, 4, 16);
      v += __shfl_xor(v, 8, 16);
      l_i[r] = l_i[r] * alpha[r] + v;
    }
#pragma unroll
    for (int t = 0; t < 4; ++t)
#pragma unroll
      for (int r = 0; r < 4; ++r) o[t][r] *= alpha[r];

    // P: C-layout -> LDS, slot-interleaved: element (row, k) at byte
    // (k>>3)*256 + row*16 + (k&7)*2.  The A-frag read then becomes LINEAR:
    // lane reads 16B at p*1024 + lane*16 (zero bank conflicts). Wave-private.
#pragma unroll
    for (int kt = 0; kt < 4; ++kt)
#pragma unroll
      for (int r = 0; r < 4; ++r) {
        const int bo = (kt * 2 + (l15 >> 3)) * 256 + (quad * 4 + r) * 16 + (l15 & 7) * 2;
        *(u16*)(PwB + bo) = f2bf(s[kt][r]);
      }

    // O += P V over both 32-key chunks (per-p P frag: minimal live registers)
#pragma unroll
    for (int p = 0; p < 2; ++p) {
      bfrag pfp = *(const bfrag*)(PwB + p * 1024 + lane * 16);
#pragma unroll
      for (int t = 0; t < 4; ++t) {
        bfrag vf = *(const bfrag*)(Vt + baseN + (((long)(t * 16 + l15)) << 11)
                                   + k0 + p * 32 + quad * 8);
        o[t] = __builtin_amdgcn_mfma_f32_16x16x32_bf16(pfp, vf, o[t], 0, 0, 0);
      }
    }
  }

  // epilogue: O/l -> [B, N, H*D] (bf16 intermediate)
#pragma unroll
  for (int r = 0; r < 4; ++r) l_i[r] = 1.0f / l_i[r];
#pragma unroll
  for (int t = 0; t < 4; ++t)
#pragma unroll
    for (int r = 0; r < 4; ++r) {
      const int row = q0 + quad * 4 + r;
      AO[(((long)(b * 2048 + row)) << 10) + h * 64 + t * 16 + l15] = f2bf(o[t][r] * l_i[r]);
    }
}

// Kernel 3: out = AO @ proj_w^T + proj_b  (f32 output)
__global__ __launch_bounds__(256) void proj_kernel(
    const u16* __restrict__ Ain, const u16* __restrict__ w,
    const float* __restrict__ pb, float* __restrict__ out)
{
  __shared__ u16 As[128 * 32];
  __shared__ u16 Bs[128 * 32];
  facc acc[4][4];
  const int m0 = blockIdx.y * 128;
  const int n0 = blockIdx.x * 128;
  gemm128_bt(Ain, w, 1024, m0, n0, As, Bs, acc);

  const int lane = threadIdx.x & 63;
  const int wv = threadIdx.x >> 6;
  const int quad = lane >> 4, l15 = lane & 15;
  const int wm = wv >> 1, wn = wv & 1;
#pragma unroll
  for (int j = 0; j < 4; ++j) {
    const int n_g = n0 + wn * 64 + j * 16 + l15;
    const float pbv = pb[n_g];
#pragma unroll
    for (int i = 0; i < 4; ++i) {
      const int mg0 = m0 + wm * 64 + i * 16 + quad * 4;
#pragma unroll
      for (int r = 0; r < 4; ++r)
        out[(((long)(mg0 + r)) << 10) + n_g] = acc[i][j][r] + pbv;
    }
  }
}

extern "C" void kernel_launch(void* const* d_in, const int* in_sizes, int n_in,
                              void* d_out, int out_size, void* d_ws, size_t ws_size,
                              hipStream_t stream)
{
  const float* x    = (const float*)d_in[0];   // [2,2048,1024] f32
  const float* bias = (const float*)d_in[1];   // [16,2048,2048] f32
  const float* qkvw = (const float*)d_in[2];   // [3072,1024] f32
  const float* qb   = (const float*)d_in[3];   // [1024] f32
  const float* vb   = (const float*)d_in[4];   // [1024] f32
  const float* pw   = (const float*)d_in[5];   // [1024,1024] f32
  const float* pb   = (const float*)d_in[6];   // [1024] f32
  float* out = (float*)d_out;                  // [2,2048,1024] f32

  char* ws = (char*)d_ws;                      // 48 MiB used
  u16* Q    = (u16*)(ws);                                  // [B,H,N,D]  8 MiB
  u16* Kd   = (u16*)(ws + (size_t)8  * 1024 * 1024);       // [B,H,N,D]  8 MiB
  u16* Vt   = (u16*)(ws + (size_t)16 * 1024 * 1024);       // [B,H,D,N]  8 MiB
  u16* AO   = (u16*)(ws + (size_t)24 * 1024 * 1024);       // [B,N,C]    8 MiB
  u16* xb   = (u16*)(ws + (size_t)32 * 1024 * 1024);       // x bf16     8 MiB
  u16* qwb  = (u16*)(ws + (size_t)40 * 1024 * 1024);       // qkv_w bf16 6 MiB
  u16* pwb  = (u16*)(ws + (size_t)46 * 1024 * 1024);       // proj_w bf16 2 MiB

  hipLaunchKernelGGL(convert_kernel, dim3(1024), dim3(256), 0, stream,
                     x, qkvw, pw, xb, qwb, pwb);
  hipLaunchKernelGGL(qkv_gemm_kernel, dim3(24, 32), dim3(256), 0, stream,
                     xb, qwb, qb, vb, Q, Kd, Vt);
  hipLaunchKernelGGL(attn_kernel, dim3(1024), dim3(256), 0, stream,
                     Q, Kd, Vt, bias, AO);
  hipLaunchKernelGGL(proj_kernel, dim3(8, 32), dim3(256), 0, stream,
                     AO, pwb, pb, out);
}

// Round 3
// 656.791 us; speedup vs baseline: 1.1180x; 1.0228x over previous
//
#include <hip/hip_runtime.h>

typedef unsigned short u16;
typedef short bfrag __attribute__((ext_vector_type(8)));   // 8 bf16 (4 VGPRs)
typedef float facc  __attribute__((ext_vector_type(4)));   // 4 fp32 acc

#define LOG2E 1.44269504088896340736f

static __device__ __forceinline__ u16 f2bf(float x) {  // RNE
  union { float f; unsigned u; } v; v.f = x;
  return (u16)((v.u + 0x7FFFu + ((v.u >> 16) & 1u)) >> 16);
}
static __device__ __forceinline__ void gload_lds16(const u16* g, u16* l) {
  __builtin_amdgcn_global_load_lds((const __attribute__((address_space(1))) void*)g,
                                   (__attribute__((address_space(3))) void*)l,
                                   16, 0, 0);
}
// bias staging: NT cache policy (aux=2) so the 268MB stream doesn't evict K/V from L2
static __device__ __forceinline__ void gload_lds16f_nt(const float* g, float* l) {
  __builtin_amdgcn_global_load_lds((const __attribute__((address_space(1))) void*)g,
                                   (__attribute__((address_space(3))) void*)l,
                                   16, 0, 2);
}

// Kernel 0: f32 -> bf16 RNE pre-convert of x, qkv_w, proj_w (memory-bound, ~48MB)
__global__ __launch_bounds__(256) void convert_kernel(
    const float* __restrict__ x, const float* __restrict__ qw, const float* __restrict__ pw,
    u16* __restrict__ xb, u16* __restrict__ qwb, u16* __restrict__ pwb)
{
  const int NX = 4 * 1024 * 1024, NQ = 3 * 1024 * 1024, NP = 1024 * 1024;
  const int total4 = (NX + NQ + NP) >> 2;
  for (int i = blockIdx.x * blockDim.x + threadIdx.x; i < total4;
       i += gridDim.x * blockDim.x) {
    const int e = i << 2;
    const float* s; u16* d; int off;
    if (e < NX)            { s = x;  d = xb;  off = e; }
    else if (e < NX + NQ)  { s = qw; d = qwb; off = e - NX; }
    else                   { s = pw; d = pwb; off = e - NX - NQ; }
    float4 v = *(const float4*)(s + off);
    ushort4 o;
    o.x = f2bf(v.x); o.y = f2bf(v.y); o.z = f2bf(v.z); o.w = f2bf(v.w);
    *(ushort4*)(d + off) = o;
  }
}

// C[m][n] = sum_k A[m][k] * B[n][k]   (B^T GEMM, bf16). 128x128 tile / 256 thr.
static __device__ __forceinline__ void gemm128_bt(
    const u16* __restrict__ A, const u16* __restrict__ B, int K,
    int m0, int n0, u16* As, u16* Bs, facc acc[4][4])
{
  const int lane = threadIdx.x & 63;
  const int wv   = threadIdx.x >> 6;
  const int quad = lane >> 4;
  const int l15  = lane & 15;
  const int wm = wv >> 1, wn = wv & 1;
  const int srow = lane >> 2;        // 16 rows per wave-call
  const int skb  = (lane & 3) * 8;   // 4 x 8 bf16 = 64B per row

  facc zero = {0.f, 0.f, 0.f, 0.f};
#pragma unroll
  for (int i = 0; i < 4; ++i)
#pragma unroll
    for (int j = 0; j < 4; ++j) acc[i][j] = zero;

  const int nIter = K >> 5;
  for (int kk = 0; kk < nIter; ++kk) {
    const int k0 = kk << 5;
    __syncthreads();                  // previous compute done before LDS overwrite
#pragma unroll
    for (int c = 0; c < 2; ++c) {
      const int seg = wv * 2 + c;     // 8 segs x 16 rows = 128 rows
      gload_lds16(A + (long)(m0 + seg * 16 + srow) * K + k0 + skb, As + seg * 512);
      gload_lds16(B + (long)(n0 + seg * 16 + srow) * K + k0 + skb, Bs + seg * 512);
    }
    __syncthreads();                  // compiler drains vmcnt before barrier
    bfrag af[4], bf[4];
#pragma unroll
    for (int i = 0; i < 4; ++i)
      af[i] = *(const bfrag*)(As + (wm * 64 + i * 16 + l15) * 32 + quad * 8);
#pragma unroll
    for (int j = 0; j < 4; ++j)
      bf[j] = *(const bfrag*)(Bs + (wn * 64 + j * 16 + l15) * 32 + quad * 8);
#pragma unroll
    for (int i = 0; i < 4; ++i)
#pragma unroll
      for (int j = 0; j < 4; ++j)
        acc[i][j] = __builtin_amdgcn_mfma_f32_16x16x32_bf16(af[i], bf[j], acc[i][j], 0, 0, 0);
  }
}

// Kernel 1: qkv = x @ qkv_w^T + qkv_b.  Scatter: Q(scaled) [B,H,N,D], K [B,H,N,D],
// V transposed [B,H,D,N] so PV's B-operand is contiguous.
__global__ __launch_bounds__(256) void qkv_gemm_kernel(
    const u16* __restrict__ x, const u16* __restrict__ w,
    const float* __restrict__ qb, const float* __restrict__ vb,
    u16* __restrict__ Q, u16* __restrict__ Kd, u16* __restrict__ Vt)
{
  __shared__ u16 As[128 * 32];
  __shared__ u16 Bs[128 * 32];
  facc acc[4][4];
  const int m0 = blockIdx.y * 128;   // rows of x (B*N = 4096)
  const int n0 = blockIdx.x * 128;   // cols (3C = 3072)
  gemm128_bt(x, w, 1024, m0, n0, As, Bs, acc);

  const int lane = threadIdx.x & 63;
  const int wv = threadIdx.x >> 6;
  const int quad = lane >> 4, l15 = lane & 15;
  const int wm = wv >> 1, wn = wv & 1;
  const int ncb = n0 + wn * 64;        // wave-uniform: one (which, h) per wave
  const int which = ncb >> 10;         // 0=Q 1=K 2=V
  const int h = (ncb >> 6) & 15;

#pragma unroll
  for (int j = 0; j < 4; ++j) {
    const int d = j * 16 + l15;        // d within head
    const int n_g = ncb + d;
#pragma unroll
    for (int i = 0; i < 4; ++i) {
      const int mg0 = m0 + wm * 64 + i * 16 + quad * 4;   // 4-aligned
      const int b  = mg0 >> 11;
      const int ns = mg0 & 2047;
      if (which == 0) {
        const float qbv = qb[n_g];
#pragma unroll
        for (int r = 0; r < 4; ++r)
          Q[(((long)(b * 16 + h) * 2048 + ns + r) << 6) + d] =
              f2bf((acc[i][j][r] + qbv) * 0.125f);          // (x@W+qb)*SCALE
      } else if (which == 1) {
#pragma unroll
        for (int r = 0; r < 4; ++r)
          Kd[(((long)(b * 16 + h) * 2048 + ns + r) << 6) + d] = f2bf(acc[i][j][r]);
      } else {
        const float vbv = vb[n_g - 2048];
        ushort4 pk;                                          // 4 consecutive n -> 8B store
        pk.x = f2bf(acc[i][j][0] + vbv);
        pk.y = f2bf(acc[i][j][1] + vbv);
        pk.z = f2bf(acc[i][j][2] + vbv);
        pk.w = f2bf(acc[i][j][3] + vbv);
        *(ushort4*)(Vt + (((long)((b * 16 + h) * 64 + d)) << 11) + ns) = pk;
      }
    }
  }
}

// Kernel 2: flash attention, K-split x2.
// Block = (h, 32 q-rows, k-half).  4 waves = {b0,b1} x {q-half}: the two batches
// share head-h bias, so bias LDS (two 16x64 f32 tiles, dbuf = 16KB) and bias
// cache pressure halve.  Grid 2048 -> 6 blocks/CU (24KB LDS), 24 waves/CU.
// Bias staged via global_load_lds (zero VGPR), source-side XOR swizzle keeps the
// LDS linear for the DMA while making the strided read 2-way-conflict-free.
// Partial (unnormalized O, m, l) in f32 -> Part; combine_kernel merges halves.
__global__ __launch_bounds__(256, 8) void attn_kernel(
    const u16* __restrict__ Q, const u16* __restrict__ Kd, const u16* __restrict__ Vt,
    const float* __restrict__ bias, float* __restrict__ Part)
{
  __shared__ u16 P[4][16 * 64];            // 8 KB: per-wave P, slot-interleaved
  __shared__ float BiasS[2][2][16 * 64];   // 16 KB: [dbuf][q-half tile][16x64]
  const int lane = threadIdx.x & 63;
  const int wv = threadIdx.x >> 6;
  const int quad = lane >> 4, l15 = lane & 15;
  const int L  = (blockIdx.x & 7) * 256 + (blockIdx.x >> 3);  // XCD-contiguous
  const int h  = L >> 7;
  const int ks = (L >> 6) & 1;
  const int qg = L & 63;
  const int q0 = qg * 32;                 // block covers head-rows [q0, q0+32)
  const int b  = wv & 1;                  // wave's batch
  const int qh = wv >> 1;                 // wave's q-half (16 rows)
  const int bh = b * 16 + h;
  const int qw = q0 + qh * 16;            // wave's first q-row
  const int ksBase = ks << 10;            // k in [ksBase, ksBase+1024)
  const long baseN = (long)bh << 17;      // bh * 2048 * 64

  // Q A-frags for this wave's 16 rows (already scaled+biased)
  bfrag qf0 = *(const bfrag*)(Q + baseN + (long)(qw + l15) * 64 + quad * 8);
  bfrag qf1 = *(const bfrag*)(Q + baseN + (long)(qw + l15) * 64 + 32 + quad * 8);

  facc o[4];
  float m_i[4], l_i[4];
  facc zero = {0.f, 0.f, 0.f, 0.f};
#pragma unroll
  for (int t = 0; t < 4; ++t) o[t] = zero;
#pragma unroll
  for (int r = 0; r < 4; ++r) { m_i[r] = -1e30f; l_i[r] = 0.f; }

  const float* bh_bias = bias + ((long)h << 22) + ((long)q0 << 11);  // bias[h][q0][0]
  char* PwB = (char*)&P[wv][0];

  // Cooperative bias staging: wave (b, qh) stages chunks {b*2, b*2+1} of tile qh.
  // Chunk c = rows 4c..4c+3 of the tile -> 1KB linear LDS (gload_lds dest must be
  // linear); the SOURCE column carries the XOR swizzle: col' = col ^ ((row&7)<<2).
  auto stage = [&](int buf, int kk) {
#pragma unroll
    for (int cc = 0; cc < 2; ++cc) {
      const int c_ = b * 2 + cc;
      const int row_ = c_ * 4 + quad;
      gload_lds16f_nt(bh_bias + (long)(qh * 16 + row_) * 2048 + kk
                        + ((l15 * 4) ^ ((row_ & 7) << 2)),
                      &BiasS[buf][qh][0] + c_ * 256);
    }
  };

  stage(0, ksBase);   // prologue: tile for iteration 0

  for (int it = 0; it < 16; ++it) {
    const int k0 = ksBase + it * 64;
    __syncthreads();   // publish staged bias tile (vmcnt drain + barrier)

    // S = Q K^T for 4 x (16q x 16k) tiles; K rows load as A-style frags = B^T operand
    facc s[4];
#pragma unroll
    for (int kt = 0; kt < 4; ++kt) {
      const u16* kb = Kd + baseN + (long)(k0 + kt * 16 + l15) * 64;
      bfrag kf0 = *(const bfrag*)(kb + quad * 8);
      bfrag kf1 = *(const bfrag*)(kb + 32 + quad * 8);
      facc z = zero;
      z = __builtin_amdgcn_mfma_f32_16x16x32_bf16(qf0, kf0, z, 0, 0, 0);
      z = __builtin_amdgcn_mfma_f32_16x16x32_bf16(qf1, kf1, z, 0, 0, 0);
      s[kt] = z;
    }

    // + rel_pos_bias from LDS (swizzled read: 2-way conflicts only = free)
    const float* bs = &BiasS[it & 1][qh][0];
#pragma unroll
    for (int kt = 0; kt < 4; ++kt)
#pragma unroll
      for (int r = 0; r < 4; ++r) {
        const int row = quad * 4 + r;
        s[kt][r] += bs[row * 64 + ((kt * 16 + l15) ^ ((row & 7) << 2))];
      }

    // issue next tile's staging AFTER consuming (no LDS-alias wait inserted);
    // cover = softmax + P + PV until next barrier's drain
    if (it + 1 < 16) stage((it + 1) & 1, k0 + 64);

    // online softmax: row reductions across the 16 lanes of the quad
    float alpha[4];
#pragma unroll
    for (int r = 0; r < 4; ++r) {
      float v = fmaxf(fmaxf(s[0][r], s[1][r]), fmaxf(s[2][r], s[3][r]));
      v = fmaxf(v, __shfl_xor(v, 1, 16));
      v = fmaxf(v, __shfl_xor(v, 2, 16));
      v = fmaxf(v, __shfl_xor(v, 4, 16));
      v = fmaxf(v, __shfl_xor(v, 8, 16));
      const float mn = fmaxf(m_i[r], v);
      alpha[r] = exp2f((m_i[r] - mn) * LOG2E);
      m_i[r] = mn;
    }
#pragma unroll
    for (int r = 0; r < 4; ++r) {
      const float p0 = exp2f((s[0][r] - m_i[r]) * LOG2E);
      const float p1 = exp2f((s[1][r] - m_i[r]) * LOG2E);
      const float p2 = exp2f((s[2][r] - m_i[r]) * LOG2E);
      const float p3 = exp2f((s[3][r] - m_i[r]) * LOG2E);
      s[0][r] = p0; s[1][r] = p1; s[2][r] = p2; s[3][r] = p3;
      float v = (p0 + p1) + (p2 + p3);
      v += __shfl_xor(v, 1, 16);
      v += __shfl_xor(v, 2, 16);
      v += __shfl_xor(v, 4, 16);
      v += __shfl_xor(v, 8, 16);
      l_i[r] = l_i[r] * alpha[r] + v;
    }
#pragma unroll
    for (int t = 0; t < 4; ++t)
#pragma unroll
      for (int r = 0; r < 4; ++r) o[t][r] *= alpha[r];

    // P: C-layout -> LDS, slot-interleaved: element (row, k) at byte
    // (k>>3)*256 + row*16 + (k&7)*2.  A-frag read is then LINEAR: lane*16B.
#pragma unroll
    for (int kt = 0; kt < 4; ++kt)
#pragma unroll
      for (int r = 0; r < 4; ++r) {
        const int bo = (kt * 2 + (l15 >> 3)) * 256 + (quad * 4 + r) * 16 + (l15 & 7) * 2;
        *(u16*)(PwB + bo) = f2bf(s[kt][r]);
      }

    // O += P V over both 32-key chunks
#pragma unroll
    for (int p = 0; p < 2; ++p) {
      bfrag pfp = *(const bfrag*)(PwB + p * 1024 + lane * 16);
#pragma unroll
      for (int t = 0; t < 4; ++t) {
        bfrag vf = *(const bfrag*)(Vt + baseN + (((long)(t * 16 + l15)) << 11)
                                   + k0 + p * 32 + quad * 8);
        o[t] = __builtin_amdgcn_mfma_f32_16x16x32_bf16(pfp, vf, o[t], 0, 0, 0);
      }
    }
  }

  // partial epilogue: unnormalized O + (m,l) in f32.  Part row stride 80 f32
  // (320B: 64B- and 16B-aligned).  Layout: [ks][bh][q][80].
  const long prBase = ((long)ks * 65536 + (long)bh * 2048 + qw) * 80;
#pragma unroll
  for (int t = 0; t < 4; ++t)
#pragma unroll
    for (int r = 0; r < 4; ++r)
      Part[prBase + (long)(quad * 4 + r) * 80 + t * 16 + l15] = o[t][r];
#pragma unroll
  for (int r = 0; r < 4; ++r)
    if (l15 < 2)
      Part[prBase + (long)(quad * 4 + r) * 80 + 64 + l15] = (l15 == 0) ? m_i[r] : l_i[r];
}

// Kernel 2b: merge the two K-half partials -> AO bf16 [B,N,H*D]
__global__ __launch_bounds__(256) void combine_kernel(
    const float* __restrict__ Part, u16* __restrict__ AO)
{
  const int lane = threadIdx.x & 63;
  const int wv = threadIdx.x >> 6;
  const long row = (long)blockIdx.x * 4 + wv;   // 0..65535 = bh*2048 + q
  const int bh = (int)(row >> 11);
  const int q  = (int)(row & 2047);
  const int b = bh >> 4, h = bh & 15;
  const float* p0 = Part + row * 80;
  const float* p1 = Part + (row + 65536) * 80;
  const float o0 = p0[lane], o1 = p1[lane];
  const float m0 = p0[64], l0 = p0[65];
  const float m1 = p1[64], l1 = p1[65];
  const float m = fmaxf(m0, m1);
  const float w0 = exp2f((m0 - m) * LOG2E);
  const float w1 = exp2f((m1 - m) * LOG2E);
  const float ov = (o0 * w0 + o1 * w1) / (l0 * w0 + l1 * w1);
  AO[(((long)(b * 2048 + q)) << 10) + h * 64 + lane] = f2bf(ov);
}

// Kernel 3: out = AO @ proj_w^T + proj_b  (f32 output)
__global__ __launch_bounds__(256) void proj_kernel(
    const u16* __restrict__ Ain, const u16* __restrict__ w,
    const float* __restrict__ pb, float* __restrict__ out)
{
  __shared__ u16 As[128 * 32];
  __shared__ u16 Bs[128 * 32];
  facc acc[4][4];
  const int m0 = blockIdx.y * 128;
  const int n0 = blockIdx.x * 128;
  gemm128_bt(Ain, w, 1024, m0, n0, As, Bs, acc);

  const int lane = threadIdx.x & 63;
  const int wv = threadIdx.x >> 6;
  const int quad = lane >> 4, l15 = lane & 15;
  const int wm = wv >> 1, wn = wv & 1;
#pragma unroll
  for (int j = 0; j < 4; ++j) {
    const int n_g = n0 + wn * 64 + j * 16 + l15;
    const float pbv = pb[n_g];
#pragma unroll
    for (int i = 0; i < 4; ++i) {
      const int mg0 = m0 + wm * 64 + i * 16 + quad * 4;
#pragma unroll
      for (int r = 0; r < 4; ++r)
        out[(((long)(mg0 + r)) << 10) + n_g] = acc[i][j][r] + pbv;
    }
  }
}

extern "C" void kernel_launch(void* const* d_in, const int* in_sizes, int n_in,
                              void* d_out, int out_size, void* d_ws, size_t ws_size,
                              hipStream_t stream)
{
  const float* x    = (const float*)d_in[0];   // [2,2048,1024] f32
  const float* bias = (const float*)d_in[1];   // [16,2048,2048] f32
  const float* qkvw = (const float*)d_in[2];   // [3072,1024] f32
  const float* qb   = (const float*)d_in[3];   // [1024] f32
  const float* vb   = (const float*)d_in[4];   // [1024] f32
  const float* pw   = (const float*)d_in[5];   // [1024,1024] f32
  const float* pb   = (const float*)d_in[6];   // [1024] f32
  float* out = (float*)d_out;                  // [2,2048,1024] f32

  char* ws = (char*)d_ws;                      // 88 MiB used
  u16* Q    = (u16*)(ws);                                  // [B,H,N,D]  8 MiB
  u16* Kd   = (u16*)(ws + (size_t)8  * 1024 * 1024);       // [B,H,N,D]  8 MiB
  u16* Vt   = (u16*)(ws + (size_t)16 * 1024 * 1024);       // [B,H,D,N]  8 MiB
  u16* AO   = (u16*)(ws + (size_t)24 * 1024 * 1024);       // [B,N,C]    8 MiB
  u16* xb   = (u16*)(ws + (size_t)32 * 1024 * 1024);       // x bf16     8 MiB
  u16* qwb  = (u16*)(ws + (size_t)40 * 1024 * 1024);       // qkv_w bf16 6 MiB
  u16* pwb  = (u16*)(ws + (size_t)46 * 1024 * 1024);       // proj_w bf16 2 MiB
  float* Part = (float*)(ws + (size_t)48 * 1024 * 1024);   // [2][32][2048][80] f32 40 MiB

  hipLaunchKernelGGL(convert_kernel, dim3(1024), dim3(256), 0, stream,
                     x, qkvw, pw, xb, qwb, pwb);
  hipLaunchKernelGGL(qkv_gemm_kernel, dim3(24, 32), dim3(256), 0, stream,
                     xb, qwb, qb, vb, Q, Kd, Vt);
  hipLaunchKernelGGL(attn_kernel, dim3(2048), dim3(256), 0, stream,
                     Q, Kd, Vt, bias, Part);
  hipLaunchKernelGGL(combine_kernel, dim3(16384), dim3(256), 0, stream,
                     Part, AO);
  hipLaunchKernelGGL(proj_kernel, dim3(8, 32), dim3(256), 0, stream,
                     AO, pwb, pb, out);
}